// Round 8
// baseline (238.985 us; speedup 1.0000x reference)
//
#include <hip/hip_runtime.h>
#include <hip/hip_bf16.h>

#define LOG2E 1.4426950408889634f

constexpr int Dn = 128;
constexpr int Nn = 16384;
constexpr int Kn = 64;
constexpr int Bn = 16;

typedef float f32x4 __attribute__((ext_vector_type(4)));
typedef unsigned int u32x4 __attribute__((ext_vector_type(4)));
typedef short short8 __attribute__((ext_vector_type(8)));

// round-to-nearest-even bf16, returned as fp32 bits with low 16 zeroed
__device__ __forceinline__ unsigned int rnhi(float f) {
    unsigned int u = __float_as_uint(f);
    return (u + 0x7FFFu + ((u >> 16) & 1u)) & 0xFFFF0000u;
}

// Prep (unchanged from round 6, verified): folds mu-normalize, exp(-log_sigma),
// factor -2, k-constant, log2e — then splits each coefficient into bf16 hi+lo
// (RNE) and writes MFMA A-frags.
// Frag layout (ushort): wfrag[(((ks*4+s)*4+mat)*64+lane)*8+j], mat 0..3 =
// {a_hi, a_lo, b_hi, b_lo}; lane = (h<<4)|(k&15); d = s*32 + 8h + j.
// The SAME (h,j)->d map is used for the X (B-operand) frags in gmm_main, so
// any hardware permutation of the MFMA contraction slots cancels.
__global__ __launch_bounds__(64) void gmm_prep(const float* __restrict__ mu,
                                               const float* __restrict__ log_sigma,
                                               const float* __restrict__ log_alpha,
                                               unsigned short* __restrict__ wfrag,
                                               float* __restrict__ cout) {
    const int k = blockIdx.x;
    const int l = threadIdx.x;        // covers d0 = 2l, d0+1
    const int d0 = 2 * l;
    float m0 = mu[k * Dn + d0];
    float m1 = mu[k * Dn + d0 + 1];
    float s0 = log_sigma[k * Dn + d0];
    float s1 = log_sigma[k * Dn + d0 + 1];
    float nrm2 = m0 * m0 + m1 * m1;
    float lss = s0 + s1;
    #pragma unroll
    for (int off = 32; off > 0; off >>= 1) {
        nrm2 += __shfl_xor(nrm2, off);
        lss  += __shfl_xor(lss, off);
    }
    const float inv_nrm = 1.0f / fmaxf(sqrtf(nrm2), 1e-12f);
    const float mn0 = m0 * inv_nrm, mn1 = m1 * inv_nrm;
    const float si0 = expf(-s0), si1 = expf(-s1);
    float mt = mn0 * mn0 * si0 + mn1 * mn1 * si1;
    #pragma unroll
    for (int off = 32; off > 0; off >>= 1) mt += __shfl_xor(mt, off);

    const float av[2] = {-si0 * LOG2E, -si1 * LOG2E};
    const float bv[2] = {2.0f * mn0 * si0 * LOG2E, 2.0f * mn1 * si1 * LOG2E};
    const int ks = k >> 4;
    #pragma unroll
    for (int dd = 0; dd < 2; ++dd) {
        const int d = d0 + dd;
        const unsigned int ah = rnhi(av[dd]);
        const unsigned int al = rnhi(av[dd] - __uint_as_float(ah));
        const unsigned int bh = rnhi(bv[dd]);
        const unsigned int bl = rnhi(bv[dd] - __uint_as_float(bh));
        const int s = d >> 5, h = (d >> 3) & 3, j = d & 7;
        const int lane = (h << 4) | (k & 15);
        const size_t base = ((size_t)((ks * 4 + s) * 4) * 64 + lane) * 8 + j;
        wfrag[base + 0 * 64 * 8] = (unsigned short)(ah >> 16);
        wfrag[base + 1 * 64 * 8] = (unsigned short)(al >> 16);
        wfrag[base + 2 * 64 * 8] = (unsigned short)(bh >> 16);
        wfrag[base + 3 * 64 * 8] = (unsigned short)(bl >> 16);
    }
    if (l == 0) cout[k] = (log_alpha[k] - 0.5f * lss - mt) * LOG2E;
}

// packed RNE f32x2 -> bf16x2 (compiler emits v_cvt_pk_bf16_f32)
__device__ __forceinline__ unsigned int pk2(float a, float b) {
    __hip_bfloat162 h = __float22bfloat162_rn(make_float2(a, b));
    unsigned int u;
    __builtin_memcpy(&u, &h, 4);
    return u;
}

// Main v9 = v8 structure with the NaN fix: v8 fed inline-asm MFMAs with
// VALU-produced (v_cvt_pk) operands — the compiler can't insert the required
// VALU-write->MFMA-read wait states inside/around asm blobs, and non-volatile
// asm MFMAs could be scheduled across the volatile s_nop guards (rule-#18
// failure mode) -> MFMA read uninitialized regs -> NaN. Fix: use the
// __builtin_amdgcn_mfma intrinsic so the compiler's hazard recognizer owns
// all wait states; delete every manual s_nop.
// Structure (unchanged): LDS-free. Each lane loads its own 8 B-frag elements
// directly from global (lane=(h<<4)|tok: 16 lanes x 4B = 4 full 64B sectors
// per dword load), splits to bf16 hi/lo in-register. Block = 128 tokens x
// all 64 k, 512 thr / 8 waves = 4 ks-strips x 2 token-halves; wave = 16k x
// 4 token-tiles (acc 16 VGPR). W loaded per-s (16 regs live). LDS = 4KB
// softmax reduction only. Same 6-term split + accumulation order as v7
// (which passed at absmax 0.0039).
// C/D: col=lane&15 (token), row=(l>>4)*4+reg (k) [m89-verified].
__global__ __launch_bounds__(512)
__attribute__((amdgpu_waves_per_eu(4, 4)))
void gmm_main(const float* __restrict__ x,
              const unsigned short* __restrict__ wf,
              const float* __restrict__ cks,
              float* __restrict__ out) {
    __shared__ float sRedM[4][128];    // per-ks token maxes
    __shared__ float sRedS[4][128];    // per-ks token sums

    const int tid = threadIdx.x;
    const int l = tid & 63;
    const int wid = __builtin_amdgcn_readfirstlane(tid >> 6);
    const int ks = wid & 3;            // k-strip: k in [16ks, 16ks+16)
    const int tp = wid >> 2;           // token-half: tiles 4tp..4tp+3
    const int h = l >> 4;              // lane's h-group (d-octet selector)
    const int b = blockIdx.y;
    const int nwin = blockIdx.x * 128;
    const float* xwin = x + (size_t)b * Dn * Nn + nwin;

    // acc init with per-k constant (folds epilogue add)
    f32x4 acc[4];
    #pragma unroll
    for (int tt = 0; tt < 4; ++tt)
        #pragma unroll
        for (int r = 0; r < 4; ++r)
            acc[tt][r] = cks[ks * 16 + h * 4 + r];

#define BC(v) __builtin_bit_cast(short8, v)
    #pragma unroll
    for (int s = 0; s < 4; ++s) {
        // W A-frags for this 32-d slice: 4 mats {a_hi,a_lo,b_hi,b_lo}
        u32x4 Ws[4];
        #pragma unroll
        for (int m = 0; m < 4; ++m)
            Ws[m] = *(const u32x4*)(wf +
                     ((size_t)((ks * 4 + s) * 4 + m) * 64 + l) * 8);

        #pragma unroll
        for (int tt = 0; tt < 4; ++tt) {
            const int ttg = tp * 4 + tt;
            const float* xtok = xwin + ttg * 16 + (l & 15);
            float xv[8];
            #pragma unroll
            for (int j = 0; j < 8; ++j)
                xv[j] = xtok[(size_t)(s * 32 + 8 * h + j) * Nn];

            u32x4 Xh, Xl, Th, Tl;
            #pragma unroll
            for (int p = 0; p < 4; ++p) {
                const float x0 = xv[2 * p], x1 = xv[2 * p + 1];
                const float t0 = x0 * x0, t1 = x1 * x1;
                const unsigned int xh = pk2(x0, x1);
                Xh[p] = xh;
                Xl[p] = pk2(x0 - __uint_as_float(xh << 16),
                            x1 - __uint_as_float(xh & 0xFFFF0000u));
                const unsigned int th = pk2(t0, t1);
                Th[p] = th;
                Tl[p] = pk2(t0 - __uint_as_float(th << 16),
                            t1 - __uint_as_float(th & 0xFFFF0000u));
            }
            acc[tt] = __builtin_amdgcn_mfma_f32_16x16x32_bf16(
                          BC(Ws[0]), BC(Th), acc[tt], 0, 0, 0);  // a_hi * t_hi
            acc[tt] = __builtin_amdgcn_mfma_f32_16x16x32_bf16(
                          BC(Ws[1]), BC(Th), acc[tt], 0, 0, 0);  // a_lo * t_hi
            acc[tt] = __builtin_amdgcn_mfma_f32_16x16x32_bf16(
                          BC(Ws[0]), BC(Tl), acc[tt], 0, 0, 0);  // a_hi * t_lo
            acc[tt] = __builtin_amdgcn_mfma_f32_16x16x32_bf16(
                          BC(Ws[2]), BC(Xh), acc[tt], 0, 0, 0);  // b_hi * x_hi
            acc[tt] = __builtin_amdgcn_mfma_f32_16x16x32_bf16(
                          BC(Ws[3]), BC(Xh), acc[tt], 0, 0, 0);  // b_lo * x_hi
            acc[tt] = __builtin_amdgcn_mfma_f32_16x16x32_bf16(
                          BC(Ws[2]), BC(Xl), acc[tt], 0, 0, 0);  // b_hi * x_lo
        }
    }
#undef BC

    // ---- softmax: per-wave (16 k) max -> cross-ks via LDS ----
    #pragma unroll
    for (int tt = 0; tt < 4; ++tt) {
        float m = fmaxf(fmaxf(acc[tt][0], acc[tt][1]),
                        fmaxf(acc[tt][2], acc[tt][3]));
        m = fmaxf(m, __shfl_xor(m, 16));
        m = fmaxf(m, __shfl_xor(m, 32));
        if (l < 16) sRedM[ks][(tp * 4 + tt) * 16 + l] = m;
    }
    __syncthreads();
    float stot[4];
    #pragma unroll
    for (int tt = 0; tt < 4; ++tt) {
        const int ttg = tp * 4 + tt;
        float m = sRedM[0][ttg * 16 + (l & 15)];
        m = fmaxf(m, sRedM[1][ttg * 16 + (l & 15)]);
        m = fmaxf(m, sRedM[2][ttg * 16 + (l & 15)]);
        m = fmaxf(m, sRedM[3][ttg * 16 + (l & 15)]);
        float ssum = 0.f;
        #pragma unroll
        for (int r = 0; r < 4; ++r) {
            acc[tt][r] = __builtin_amdgcn_exp2f(acc[tt][r] - m);
            ssum += acc[tt][r];
        }
        ssum += __shfl_xor(ssum, 16);
        ssum += __shfl_xor(ssum, 32);
        if (l < 16) sRedS[ks][ttg * 16 + l] = ssum;
    }
    __syncthreads();
    #pragma unroll
    for (int tt = 0; tt < 4; ++tt) {
        const int ttg = tp * 4 + tt;
        stot[tt] = sRedS[0][ttg * 16 + (l & 15)] + sRedS[1][ttg * 16 + (l & 15)] +
                   sRedS[2][ttg * 16 + (l & 15)] + sRedS[3][ttg * 16 + (l & 15)];
    }

    // ---- store: out[b][ks*16 + h*4 + r][nwin + ttg*16 + (l&15)] ----
    #pragma unroll
    for (int tt = 0; tt < 4; ++tt) {
        const int ttg = tp * 4 + tt;
        const float inv = 1.0f / stot[tt];
        float* op = out + ((size_t)(b * Kn + ks * 16 + h * 4)) * Nn +
                    nwin + ttg * 16 + (l & 15);
        #pragma unroll
        for (int r = 0; r < 4; ++r) {
            *op = acc[tt][r] * inv;
            op += Nn;
        }
    }
}

extern "C" void kernel_launch(void* const* d_in, const int* in_sizes, int n_in,
                              void* d_out, int out_size, void* d_ws, size_t ws_size,
                              hipStream_t stream) {
    const float* x  = (const float*)d_in[0];
    const float* mu = (const float*)d_in[1];
    const float* ls = (const float*)d_in[2];
    const float* la = (const float*)d_in[3];
    float* out = (float*)d_out;

    unsigned short* wbuf = (unsigned short*)d_ws;                 // 64 KB frags
    float* cbuf = (float*)((char*)d_ws + 65536);                  // 64 consts

    gmm_prep<<<dim3(Kn), dim3(64), 0, stream>>>(mu, ls, la, wbuf, cbuf);
    gmm_main<<<dim3(Nn / 128, Bn), dim3(512), 0, stream>>>(x, wbuf, cbuf, out);
}

// Round 9
// 221.935 us; speedup vs baseline: 1.0768x; 1.0768x over previous
//
#include <hip/hip_runtime.h>
#include <hip/hip_bf16.h>

#define LOG2E 1.4426950408889634f

constexpr int Dn = 128;
constexpr int Nn = 16384;
constexpr int Kn = 64;
constexpr int Bn = 16;

typedef float f32x4 __attribute__((ext_vector_type(4)));
typedef unsigned int u32x4 __attribute__((ext_vector_type(4)));
typedef short short8 __attribute__((ext_vector_type(8)));

// round-to-nearest-even bf16, returned as fp32 bits with low 16 zeroed
__device__ __forceinline__ unsigned int rnhi(float f) {
    unsigned int u = __float_as_uint(f);
    return (u + 0x7FFFu + ((u >> 16) & 1u)) & 0xFFFF0000u;
}

// Prep (unchanged since round 6, verified twice): folds mu-normalize,
// exp(-log_sigma), factor -2, k-constant, log2e — splits each coefficient
// into bf16 hi+lo (RNE) and writes MFMA A-frags.
// Frag layout (ushort): wfrag[(((ks*4+s)*4+mat)*64+lane)*8+j], mat 0..3 =
// {a_hi, a_lo, b_hi, b_lo}; lane = (h<<4)|(k&15); d = s*32 + 8h + j.
// The SAME (h,j)->d map is used for the X (B-operand) frags in gmm_main, so
// any hardware permutation of the MFMA contraction slots cancels.
__global__ __launch_bounds__(64) void gmm_prep(const float* __restrict__ mu,
                                               const float* __restrict__ log_sigma,
                                               const float* __restrict__ log_alpha,
                                               unsigned short* __restrict__ wfrag,
                                               float* __restrict__ cout) {
    const int k = blockIdx.x;
    const int l = threadIdx.x;        // covers d0 = 2l, d0+1
    const int d0 = 2 * l;
    float m0 = mu[k * Dn + d0];
    float m1 = mu[k * Dn + d0 + 1];
    float s0 = log_sigma[k * Dn + d0];
    float s1 = log_sigma[k * Dn + d0 + 1];
    float nrm2 = m0 * m0 + m1 * m1;
    float lss = s0 + s1;
    #pragma unroll
    for (int off = 32; off > 0; off >>= 1) {
        nrm2 += __shfl_xor(nrm2, off);
        lss  += __shfl_xor(lss, off);
    }
    const float inv_nrm = 1.0f / fmaxf(sqrtf(nrm2), 1e-12f);
    const float mn0 = m0 * inv_nrm, mn1 = m1 * inv_nrm;
    const float si0 = expf(-s0), si1 = expf(-s1);
    float mt = mn0 * mn0 * si0 + mn1 * mn1 * si1;
    #pragma unroll
    for (int off = 32; off > 0; off >>= 1) mt += __shfl_xor(mt, off);

    const float av[2] = {-si0 * LOG2E, -si1 * LOG2E};
    const float bv[2] = {2.0f * mn0 * si0 * LOG2E, 2.0f * mn1 * si1 * LOG2E};
    const int ks = k >> 4;
    #pragma unroll
    for (int dd = 0; dd < 2; ++dd) {
        const int d = d0 + dd;
        const unsigned int ah = rnhi(av[dd]);
        const unsigned int al = rnhi(av[dd] - __uint_as_float(ah));
        const unsigned int bh = rnhi(bv[dd]);
        const unsigned int bl = rnhi(bv[dd] - __uint_as_float(bh));
        const int s = d >> 5, h = (d >> 3) & 3, j = d & 7;
        const int lane = (h << 4) | (k & 15);
        const size_t base = ((size_t)((ks * 4 + s) * 4) * 64 + lane) * 8 + j;
        wfrag[base + 0 * 64 * 8] = (unsigned short)(ah >> 16);
        wfrag[base + 1 * 64 * 8] = (unsigned short)(al >> 16);
        wfrag[base + 2 * 64 * 8] = (unsigned short)(bh >> 16);
        wfrag[base + 3 * 64 * 8] = (unsigned short)(bl >> 16);
    }
    if (l == 0) cout[k] = (log_alpha[k] - 0.5f * lss - mt) * LOG2E;
}

// packed RNE f32x2 -> bf16x2 (compiler emits v_cvt_pk_bf16_f32)
__device__ __forceinline__ unsigned int pk2(float a, float b) {
    __hip_bfloat162 h = __float22bfloat162_rn(make_float2(a, b));
    unsigned int u;
    __builtin_memcpy(&u, &h, 4);
    return u;
}

// Main v10 = v7's stage-once LDS amortization + v9's builtin-MFMA compute,
// restructured as an s-sliced double-buffered pipeline. v9 regressed (113us
// vs v7's <79) because each of the 4 ks-waves redundantly re-loaded AND
// re-converted the same x (4x loads, 4x cvt VALU) at 37% occupancy; v7's
// weakness was the monolithic stage->sync->compute serialization. Here:
// per 32-d slice s: [issue s+1 global loads] -> [compute s: 4 W loads +
// 16 ds_read_b128 + 24 MFMA per wave] -> [cvt + ds_write s+1] -> barrier
// (T14 load-early/write-late; compute covers the load latency). x is read
// and converted exactly ONCE per block. Block = 128 tokens x all 64 k,
// 512 thr / 8 waves = 4 ks-strips x 2 token-halves; wave = 16k x 4 tiles.
// LDS = 2x32KB frag dbuf + 4KB softmax red -> 2 blocks/CU = 4 waves/SIMD.
// Same 6-term split + MFMA accumulation order as v7/v9 (absmax 0.0039).
// C/D: col=lane&15 (token), row=(l>>4)*4+reg (k) [m89-verified].
__global__ __launch_bounds__(512)
__attribute__((amdgpu_waves_per_eu(4, 4)))
void gmm_main(const float* __restrict__ x,
              const unsigned short* __restrict__ wf,
              const float* __restrict__ cks,
              float* __restrict__ out) {
    __shared__ unsigned short sF[2][4][8][64][8];  // [buf][mat][tt][lane][j] 64KB
    __shared__ float sRedM[4][128];                // per-ks token maxes
    __shared__ float sRedS[4][128];                // per-ks token sums

    const int tid = threadIdx.x;
    const int l = tid & 63;
    const int wid = __builtin_amdgcn_readfirstlane(tid >> 6);
    const int ks = wid & 3;            // k-strip: k in [16ks, 16ks+16)
    const int tp = wid >> 2;           // token-half: tiles 4tp..4tp+3
    const int h = l >> 4;              // lane's h-group (d-octet selector)
    const int col = l & 15;            // lane's token column
    const int b = blockIdx.y;
    const int nwin = blockIdx.x * 128;
    const float* xwin = x + (size_t)b * Dn * Nn + nwin;

    // staging identity: thread owns (token stok, d-octet sdg) of each slice
    const int stok = tid & 127;
    const int sdg = tid >> 7;
    const int stt = stok >> 4;
    const int slane = (sdg << 4) | (stok & 15);
    const float* sx = xwin + stok + (size_t)(sdg * 8) * Nn;

    // acc init with per-k constant (folds epilogue add)
    f32x4 acc[4];
    #pragma unroll
    for (int tt = 0; tt < 4; ++tt)
        #pragma unroll
        for (int r = 0; r < 4; ++r)
            acc[tt][r] = cks[ks * 16 + h * 4 + r];

    auto cvtwrite = [&](int buf, const float* xv) {
        u32x4 Xh, Xl, Th, Tl;
        #pragma unroll
        for (int p = 0; p < 4; ++p) {
            const float x0 = xv[2 * p], x1 = xv[2 * p + 1];
            const float t0 = x0 * x0, t1 = x1 * x1;
            const unsigned int xh = pk2(x0, x1);
            Xh[p] = xh;
            Xl[p] = pk2(x0 - __uint_as_float(xh << 16),
                        x1 - __uint_as_float(xh & 0xFFFF0000u));
            const unsigned int th = pk2(t0, t1);
            Th[p] = th;
            Tl[p] = pk2(t0 - __uint_as_float(th << 16),
                        t1 - __uint_as_float(th & 0xFFFF0000u));
        }
        *(u32x4*)&sF[buf][0][stt][slane][0] = Xh;
        *(u32x4*)&sF[buf][1][stt][slane][0] = Xl;
        *(u32x4*)&sF[buf][2][stt][slane][0] = Th;
        *(u32x4*)&sF[buf][3][stt][slane][0] = Tl;
    };

    // prologue: slice 0 -> buf0
    {
        float xr[8];
        #pragma unroll
        for (int j = 0; j < 8; ++j) xr[j] = sx[(size_t)j * Nn];
        cvtwrite(0, xr);
    }
    __syncthreads();

#define BC(v) __builtin_bit_cast(short8, v)
    #pragma unroll
    for (int s = 0; s < 4; ++s) {
        // issue next slice's global loads EARLY (latency hides under compute)
        float xn[8];
        if (s < 3) {
            #pragma unroll
            for (int j = 0; j < 8; ++j)
                xn[j] = sx[(size_t)((s + 1) * 32 + j) * Nn];
        }

        // ---- compute slice s from buf[s&1] ----
        u32x4 Ws[4];
        #pragma unroll
        for (int m = 0; m < 4; ++m)
            Ws[m] = *(const u32x4*)(wf +
                     ((size_t)((ks * 4 + s) * 4 + m) * 64 + l) * 8);

        #pragma unroll
        for (int tt = 0; tt < 4; ++tt) {
            const int ttg = tp * 4 + tt;
            const u32x4 Xh = *(const u32x4*)&sF[s & 1][0][ttg][l][0];
            const u32x4 Xl = *(const u32x4*)&sF[s & 1][1][ttg][l][0];
            const u32x4 Th = *(const u32x4*)&sF[s & 1][2][ttg][l][0];
            const u32x4 Tl = *(const u32x4*)&sF[s & 1][3][ttg][l][0];
            acc[tt] = __builtin_amdgcn_mfma_f32_16x16x32_bf16(
                          BC(Ws[0]), BC(Th), acc[tt], 0, 0, 0);  // a_hi * t_hi
            acc[tt] = __builtin_amdgcn_mfma_f32_16x16x32_bf16(
                          BC(Ws[1]), BC(Th), acc[tt], 0, 0, 0);  // a_lo * t_hi
            acc[tt] = __builtin_amdgcn_mfma_f32_16x16x32_bf16(
                          BC(Ws[0]), BC(Tl), acc[tt], 0, 0, 0);  // a_hi * t_lo
            acc[tt] = __builtin_amdgcn_mfma_f32_16x16x32_bf16(
                          BC(Ws[2]), BC(Xh), acc[tt], 0, 0, 0);  // b_hi * x_hi
            acc[tt] = __builtin_amdgcn_mfma_f32_16x16x32_bf16(
                          BC(Ws[3]), BC(Xh), acc[tt], 0, 0, 0);  // b_lo * x_hi
            acc[tt] = __builtin_amdgcn_mfma_f32_16x16x32_bf16(
                          BC(Ws[2]), BC(Xl), acc[tt], 0, 0, 0);  // b_hi * x_lo
        }

        // ---- write next slice's frags, then barrier ----
        if (s < 3) {
            cvtwrite((s + 1) & 1, xn);
            __syncthreads();
        }
    }
#undef BC

    // ---- softmax: per-wave (16 k) max -> cross-ks via LDS ----
    #pragma unroll
    for (int tt = 0; tt < 4; ++tt) {
        float m = fmaxf(fmaxf(acc[tt][0], acc[tt][1]),
                        fmaxf(acc[tt][2], acc[tt][3]));
        m = fmaxf(m, __shfl_xor(m, 16));
        m = fmaxf(m, __shfl_xor(m, 32));
        if (l < 16) sRedM[ks][tp * 64 + tt * 16 + l] = m;
    }
    __syncthreads();
    float stot[4];
    #pragma unroll
    for (int tt = 0; tt < 4; ++tt) {
        const int idx = tp * 64 + tt * 16 + col;
        float m = sRedM[0][idx];
        m = fmaxf(m, sRedM[1][idx]);
        m = fmaxf(m, sRedM[2][idx]);
        m = fmaxf(m, sRedM[3][idx]);
        float ssum = 0.f;
        #pragma unroll
        for (int r = 0; r < 4; ++r) {
            acc[tt][r] = __builtin_amdgcn_exp2f(acc[tt][r] - m);
            ssum += acc[tt][r];
        }
        ssum += __shfl_xor(ssum, 16);
        ssum += __shfl_xor(ssum, 32);
        if (l < 16) sRedS[ks][tp * 64 + tt * 16 + l] = ssum;
    }
    __syncthreads();
    #pragma unroll
    for (int tt = 0; tt < 4; ++tt) {
        const int idx = tp * 64 + tt * 16 + col;
        stot[tt] = sRedS[0][idx] + sRedS[1][idx] + sRedS[2][idx] + sRedS[3][idx];
    }

    // ---- store: out[b][ks*16 + h*4 + r][nwin + tp*64 + tt*16 + col] ----
    #pragma unroll
    for (int tt = 0; tt < 4; ++tt) {
        const float inv = 1.0f / stot[tt];
        float* op = out + ((size_t)(b * Kn + ks * 16 + h * 4)) * Nn +
                    nwin + tp * 64 + tt * 16 + col;
        #pragma unroll
        for (int r = 0; r < 4; ++r) {
            *op = acc[tt][r] * inv;
            op += Nn;
        }
    }
}

extern "C" void kernel_launch(void* const* d_in, const int* in_sizes, int n_in,
                              void* d_out, int out_size, void* d_ws, size_t ws_size,
                              hipStream_t stream) {
    const float* x  = (const float*)d_in[0];
    const float* mu = (const float*)d_in[1];
    const float* ls = (const float*)d_in[2];
    const float* la = (const float*)d_in[3];
    float* out = (float*)d_out;

    unsigned short* wbuf = (unsigned short*)d_ws;                 // 64 KB frags
    float* cbuf = (float*)((char*)d_ws + 65536);                  // 64 consts

    gmm_prep<<<dim3(Kn), dim3(64), 0, stream>>>(mu, ls, la, wbuf, cbuf);
    gmm_main<<<dim3(Nn / 128, Bn), dim3(512), 0, stream>>>(x, wbuf, cbuf, out);
}